// Round 14
// baseline (1768.061 us; speedup 1.0000x reference)
//
#include <hip/hip_runtime.h>
#include <hip/hip_bf16.h>
#include <stdint.h>

typedef __bf16 bf16x8 __attribute__((ext_vector_type(8)));
typedef float f32x4 __attribute__((ext_vector_type(4)));

// ---- helpers ------------------------------------------------------------

__device__ inline void gload_lds16(const void* g, void* lds) {
  __builtin_amdgcn_global_load_lds(
      (const __attribute__((address_space(1))) uint32_t*)(uintptr_t)g,
      (__attribute__((address_space(3))) uint32_t*)(uintptr_t)lds,
      16, 0, 0);
}

// Ordered LDS vector read (issue order preserved; lgkm counted exact).
__device__ inline bf16x8 ds_readv(uint32_t addr) {
  bf16x8 r;
  asm volatile("ds_read_b128 %0, %1" : "=v"(r) : "v"(addr));
  return r;
}

// Ordered global vector load direct to regs (vmcnt-counted with stages).
#define GLB(dst, p, OFF)                                            \
  asm volatile("global_load_dwordx4 %0, %1, off offset:" #OFF       \
               : "=v"(dst) : "v"(p))

#define LGKM(N) do {                                             \
    asm volatile("s_waitcnt lgkmcnt(" #N ")" ::: "memory");      \
    __builtin_amdgcn_sched_barrier(0);                           \
  } while (0)
#define VM(N) do {                                               \
    asm volatile("s_waitcnt vmcnt(" #N ")" ::: "memory");        \
    __builtin_amdgcn_sched_barrier(0);                           \
  } while (0)

__device__ inline short f2bf(float f) {
  union { float f; uint32_t u; } x; x.f = f;
  uint32_t u = x.u;
  u += 0x7fffu + ((u >> 16) & 1u);   // RNE
  return (short)(u >> 16);
}

#define BAR() do { asm volatile("" ::: "memory"); \
                   __builtin_amdgcn_s_barrier();  \
                   asm volatile("" ::: "memory"); } while (0)

// ---- fp32 -> bf16 convert (vectorized) ----------------------------------

__global__ __launch_bounds__(256) void cvt_f32_bf16(
    const float* __restrict__ in, short* __restrict__ out, int n4) {
  int i = blockIdx.x * 256 + threadIdx.x;
  if (i < n4) {
    float4 v = reinterpret_cast<const float4*>(in)[i];
    short4 o;
    o.x = f2bf(v.x); o.y = f2bf(v.y); o.z = f2bf(v.z); o.w = f2bf(v.w);
    reinterpret_cast<short4*>(out)[i] = o;
  }
}

// ---- GEMM: C[M,N] = A[M,K] @ B[N,K]^T, bf16 in, fp32 acc ---------------
// B-DIRECT variant: B fragments load global->registers (no B LDS at all).
// Rationale: DS service (24 b128/wave/tile ~ 2300 cyc/CU) ~= MFMA (2484)
// and never overlaps past ~15% in 11 schedule variants. B rows have only
// 2-wave reuse (wr=0/1 at same wc, identical addresses -> L1/L2 hit), so
// direct loads cut DS reads to 16/wave/tile (1536 cyc < MFMA) and LDS to
// 64 KiB, with 1 barrier + 2 counted VMs per tile.
//
// 256x256 tile, BK=64, 8 waves (2Mx4N), per-wave 128x64 = acc[8][4] of
// mfma_f32_16x16x32_bf16 (swapped operands, verified r5-r13).
// LDS (A only): 2 buf x 2 slots x [128x64] bf16 = 64 KiB;
//   A0=+0 (m-frags 0-3), A1=+16384 (m 4-7); buf1=+32768.
//   Swizzle addr = slotrow*128 + ((kk*4+kq)^(fr&7))*16 (0-conflict).
// B frags: bq[n][kk] = B[bcol*256 + wc*64 + n*16 + fr][kt*64+kk*32+kq*8],
//   4 per-lane pointers (n), kk via offset:64; advance +64 elems/tile.
//   Double-buffered reg sets X/Y (2x-unrolled loop, static names).
//
// Per tile t (cur=t&1, cb=cur*32768; bqC ready-in-flight on entry):
//   RD_A0(cur)(8 ds) | stage A0,A1(t+1)->nxt (4 gl, FIRST) |
//   sched_barrier | BFRAG(t+1)->other set (8 gl) |
//   VM(12) [waits bqC: 20-12=8 oldest... retires exactly bq(t)] |
//   LGKM(0) | Q1(a0q,b0-1) | RD_A1(cur)(8 ds) | Q2(a0q,b2-3) |
//   LGKM(0) | Q3(a1q,b2-3) Q4(a1q,b0-1) | VM(8) [stage done] | BAR
// Ledger: entering t outstanding = bq(t)[8]; +4 stage +8 bfrag = 20;
//   VM(12) retires oldest 8 = bq(t) (issued in t-1, full tile latency).
//   VM(8): 12 outstanding -> retires stage(t+1) before the publish BAR.
//   Stage-before-bfrag order pinned by sched_barrier(0) (vmcnt suffix
//   rule needs it). Clobber: stage into buf[nxt]; nxt's reads completed
//   (LGKM(0)) before end-BAR(t-1) -> 1-barrier distance safe.
// Prologue: stage A(0) -> bfrag(0)->X -> VM(8) [A(0) landed] -> BAR.
// Tail t=nk-1: no stage/bfrag; VM(0) waits bq; no end BAR.
// Epilogue (verified r5-r13): lane&15=M-row, 4 acc regs = 4 consecutive
// N-cols. EPI=0: bias+relu^2->bf16 (short4); EPI=1: bias->f32 (float4).

template <int EPI>
__global__ __launch_bounds__(512, 2) void gemm_bt(
    const short* __restrict__ A, const short* __restrict__ B,
    const float* __restrict__ bias, void* __restrict__ Cout,
    int M, int N, int K) {
  __shared__ __align__(16) short lds[2][2][128 * 64];   // 64 KiB, A only

  const int tid  = threadIdx.x;
  const int wave = tid >> 6;
  const int lane = tid & 63;
  const int wr = wave >> 2;          // 0..1 -> M half (128 rows)
  const int wc = wave & 3;           // 0..3 -> N quarter (64 cols)
  const int fr = lane & 15, kq = lane >> 4;

  // T1: bijective XCD swizzle (nwg % 8 == 0), column-major in-chunk
  const int nwg = gridDim.x;
  const int w = (blockIdx.x & 7) * (nwg >> 3) + (blockIdx.x >> 3);
  const int gy = M >> 8;
  const int brow = w % gy;
  const int bcol = w / gy;

  f32x4 acc[8][4];
#pragma unroll
  for (int m = 0; m < 8; ++m)
#pragma unroll
    for (int n = 0; n < 4; ++n)
      acc[m][n] = (f32x4){0.f, 0.f, 0.f, 0.f};

  const int nk = K >> 6;             // K-tiles of 64 (even; >=4)

  // ---- A fragment read addresses (buf0); buf1 = +32768 at use site
  const uint32_t LB = (uint32_t)(uintptr_t)&lds[0][0][0];
  uint32_t aA[4][2];
#pragma unroll
  for (int m = 0; m < 4; ++m)
#pragma unroll
    for (int kk = 0; kk < 2; ++kk) {
      int r = wr * 64 + m * 16 + fr;
      int g = r * 8 + kk * 4 + kq;
      aA[m][kk] = LB + (uint32_t)((g ^ (r & 7)) * 16);
    }

  // ---- A stage source addressing (inverse swizzle on global side)
  const int i0 = tid;
  const int gl0 = i0 ^ ((i0 >> 3) & 7);
  const int r0 = gl0 >> 3, c0 = gl0 & 7;
  const size_t rstep = (size_t)128 * K;

  const short* pA[2];
#pragma unroll
  for (int h = 0; h < 2; ++h)
    pA[h] = A + (size_t)(brow * 256 + h * 64 + r0) * K + c0 * 8;

  // ---- B fragment global pointers (per lane), 4 rows (n), kk via imm
  const short* pBF[4];
#pragma unroll
  for (int n = 0; n < 4; ++n)
    pBF[n] = B + (size_t)(bcol * 256 + wc * 64 + n * 16 + fr) * K + kq * 8;

  const int dst0 = wave * 512, dst1 = 4096 + wave * 512;  // shorts in slot

#define STAGE(p, buf, slot)                              \
  do {                                                   \
    short* base_ = &lds[buf][slot][0];                   \
    gload_lds16((p), base_ + dst0);                      \
    gload_lds16((p) + rstep, base_ + dst1);              \
    (p) += 64;                                           \
  } while (0)

  // ---- fragment regs
  bf16x8 a0q[4][2], a1q[4][2];
  bf16x8 bqX[4][2], bqY[4][2];       // double-buffered B sets

  auto BFRAG = [&](bf16x8 (&bs)[4][2]) {
    GLB(bs[0][0], pBF[0], 0);  GLB(bs[0][1], pBF[0], 64);
    GLB(bs[1][0], pBF[1], 0);  GLB(bs[1][1], pBF[1], 64);
    GLB(bs[2][0], pBF[2], 0);  GLB(bs[2][1], pBF[2], 64);
    GLB(bs[3][0], pBF[3], 0);  GLB(bs[3][1], pBF[3], 64);
    pBF[0] += 64; pBF[1] += 64; pBF[2] += 64; pBF[3] += 64;
  };
  auto RD_A0 = [&](uint32_t cb) {
#pragma unroll
    for (int m = 0; m < 4; ++m)
#pragma unroll
      for (int kk = 0; kk < 2; ++kk)
        a0q[m][kk] = ds_readv(aA[m][kk] + cb);
  };
  auto RD_A1 = [&](uint32_t cb) {
#pragma unroll
    for (int m = 0; m < 4; ++m)
#pragma unroll
      for (int kk = 0; kk < 2; ++kk)
        a1q[m][kk] = ds_readv(aA[m][kk] + cb + 16384u);
  };
  auto Q1 = [&](bf16x8 (&bs)[4][2]) {
#pragma unroll
    for (int m = 0; m < 4; ++m)
#pragma unroll
      for (int n = 0; n < 2; ++n)
#pragma unroll
        for (int kk = 0; kk < 2; ++kk)
          acc[m][n] = __builtin_amdgcn_mfma_f32_16x16x32_bf16(
              bs[n][kk], a0q[m][kk], acc[m][n], 0, 0, 0);
  };
  auto Q2 = [&](bf16x8 (&bs)[4][2]) {
#pragma unroll
    for (int m = 0; m < 4; ++m)
#pragma unroll
      for (int n = 0; n < 2; ++n)
#pragma unroll
        for (int kk = 0; kk < 2; ++kk)
          acc[m][n + 2] = __builtin_amdgcn_mfma_f32_16x16x32_bf16(
              bs[n + 2][kk], a0q[m][kk], acc[m][n + 2], 0, 0, 0);
  };
  auto Q3 = [&](bf16x8 (&bs)[4][2]) {
#pragma unroll
    for (int m = 0; m < 4; ++m)
#pragma unroll
      for (int n = 0; n < 2; ++n)
#pragma unroll
        for (int kk = 0; kk < 2; ++kk)
          acc[m + 4][n + 2] = __builtin_amdgcn_mfma_f32_16x16x32_bf16(
              bs[n + 2][kk], a1q[m][kk], acc[m + 4][n + 2], 0, 0, 0);
  };
  auto Q4 = [&](bf16x8 (&bs)[4][2]) {
#pragma unroll
    for (int m = 0; m < 4; ++m)
#pragma unroll
      for (int n = 0; n < 2; ++n)
#pragma unroll
        for (int kk = 0; kk < 2; ++kk)
          acc[m + 4][n] = __builtin_amdgcn_mfma_f32_16x16x32_bf16(
              bs[n][kk], a1q[m][kk], acc[m + 4][n], 0, 0, 0);
  };

#define PRIO_ON  __builtin_amdgcn_s_setprio(1)
#define PRIO_OFF __builtin_amdgcn_s_setprio(0)

  // ---- body: one K-tile ----
  auto body = [&](int t, uint32_t cb, int nxt,
                  bf16x8 (&bqC)[4][2], bf16x8 (&bqN)[4][2]) {
    const bool s1 = (t + 1) < nk;
    RD_A0(cb);                                  // 8 ds (lgkm)
    if (s1) { STAGE(pA[0], nxt, 0); STAGE(pA[1], nxt, 1); }   // 4 gl
    __builtin_amdgcn_sched_barrier(0);          // pin stage-before-bfrag
    if (s1) BFRAG(bqN);                         // 8 gl
    if (s1) { VM(12); } else { VM(0); }         // bqC ready
    LGKM(0);                                    // a0q ready
    PRIO_ON; Q1(bqC); PRIO_OFF;
    RD_A1(cb);                                  // 8 ds, serviced under Q2
    PRIO_ON; Q2(bqC); PRIO_OFF;
    LGKM(0);                                    // a1q ready
    PRIO_ON; Q3(bqC); Q4(bqC); PRIO_OFF;
    if (s1) { VM(8); BAR(); }                   // stage(t+1) done; publish
  };

  // ---- prologue: stage A(0), load bfrag(0)->X, publish A(0).
  STAGE(pA[0], 0, 0);
  STAGE(pA[1], 0, 1);
  __builtin_amdgcn_sched_barrier(0);
  BFRAG(bqX);
  VM(8);                 // A(0) landed (oldest 4 of 12), bfrag(0) in flight
  BAR();

  for (int t = 0; t < nk; t += 2) {
    body(t,     0u,      1, bqX, bqY);
    body(t + 1, 32768u,  0, bqY, bqX);
  }

  // ---- epilogue (verified r5-r13): row = m*16+fr, cols = n*16+q*4+{0..3}
  const int q = lane >> 4;
  if (EPI == 0) {
    short* C = (short*)Cout;
#pragma unroll
    for (int m = 0; m < 8; ++m) {
      const int row = brow * 256 + wr * 128 + m * 16 + fr;
#pragma unroll
      for (int n = 0; n < 4; ++n) {
        const int col = bcol * 256 + wc * 64 + n * 16 + q * 4;
        const float4 bv = *(const float4*)&bias[col];
        short4 o;
        float v0 = acc[m][n][0] + bv.x; v0 = v0 > 0.f ? v0 * v0 : 0.f;
        float v1 = acc[m][n][1] + bv.y; v1 = v1 > 0.f ? v1 * v1 : 0.f;
        float v2 = acc[m][n][2] + bv.z; v2 = v2 > 0.f ? v2 * v2 : 0.f;
        float v3 = acc[m][n][3] + bv.w; v3 = v3 > 0.f ? v3 * v3 : 0.f;
        o.x = f2bf(v0); o.y = f2bf(v1); o.z = f2bf(v2); o.w = f2bf(v3);
        *(short4*)&C[(size_t)row * N + col] = o;
      }
    }
  } else {
    float* C = (float*)Cout;
#pragma unroll
    for (int m = 0; m < 8; ++m) {
      const int row = brow * 256 + wr * 128 + m * 16 + fr;
#pragma unroll
      for (int n = 0; n < 4; ++n) {
        const int col = bcol * 256 + wc * 64 + n * 16 + q * 4;
        const float4 bv = *(const float4*)&bias[col];
        float4 o;
        o.x = acc[m][n][0] + bv.x;
        o.y = acc[m][n][1] + bv.y;
        o.z = acc[m][n][2] + bv.z;
        o.w = acc[m][n][3] + bv.w;
        *(float4*)&C[(size_t)row * N + col] = o;
      }
    }
  }
#undef STAGE
}

// ---- launch -------------------------------------------------------------

extern "C" void kernel_launch(void* const* d_in, const int* in_sizes, int n_in,
                              void* d_out, int out_size, void* d_ws,
                              size_t ws_size, hipStream_t stream) {
  const float* x  = (const float*)d_in[0];
  const float* w1 = (const float*)d_in[1];
  const float* b1 = (const float*)d_in[2];
  const float* w2 = (const float*)d_in[3];
  const float* b2 = (const float*)d_in[4];
  float* out = (float*)d_out;

  const int H = in_sizes[2];            // 8192
  const int D = in_sizes[4];            // 2048
  const int M = in_sizes[0] / D;        // B*S = 8192

  short* xb  = (short*)d_ws;                 // M*D
  short* w1b = xb  + (size_t)M * D;          // H*D
  short* w2b = w1b + (size_t)H * D;          // D*H
  short* act = w2b + (size_t)D * H;          // M*H

  {
    int n4 = (M * D) / 4;
    cvt_f32_bf16<<<(n4 + 255) / 256, 256, 0, stream>>>(x, xb, n4);
    n4 = (H * D) / 4;
    cvt_f32_bf16<<<(n4 + 255) / 256, 256, 0, stream>>>(w1, w1b, n4);
    n4 = (D * H) / 4;
    cvt_f32_bf16<<<(n4 + 255) / 256, 256, 0, stream>>>(w2, w2b, n4);
  }

  // GEMM1: [M,D] @ [H,D]^T -> sqrelu -> act[M,H] (bf16)
  gemm_bt<0><<<(M / 256) * (H / 256), 512, 0, stream>>>(
      xb, w1b, b1, (void*)act, M, H, D);
  // GEMM2: [M,H] @ [D,H]^T -> + b2 -> out[M,D] (f32)
  gemm_bt<1><<<(M / 256) * (D / 256), 512, 0, stream>>>(
      act, w2b, b2, (void*)out, M, D, H);
}

// Round 15
// 544.058 us; speedup vs baseline: 3.2498x; 3.2498x over previous
//
#include <hip/hip_runtime.h>
#include <hip/hip_bf16.h>
#include <stdint.h>

typedef __bf16 bf16x8 __attribute__((ext_vector_type(8)));
typedef float f32x4 __attribute__((ext_vector_type(4)));

// ---- helpers ------------------------------------------------------------

__device__ inline void gload_lds16(const void* g, void* lds) {
  __builtin_amdgcn_global_load_lds(
      (const __attribute__((address_space(1))) uint32_t*)(uintptr_t)g,
      (__attribute__((address_space(3))) uint32_t*)(uintptr_t)lds,
      16, 0, 0);
}

// Ordered LDS vector read (volatile asm: issue order preserved; DS
// completion in-order per wave -> counted lgkmcnt is exact).
__device__ inline bf16x8 ds_readv(uint32_t addr) {
  bf16x8 r;
  asm volatile("ds_read_b128 %0, %1" : "=v"(r) : "v"(addr));
  return r;
}

#define LGKM(N) do {                                             \
    asm volatile("s_waitcnt lgkmcnt(" #N ")" ::: "memory");      \
    __builtin_amdgcn_sched_barrier(0);                           \
  } while (0)
#define VM(N) do {                                               \
    asm volatile("s_waitcnt vmcnt(" #N ")" ::: "memory");        \
    __builtin_amdgcn_sched_barrier(0);                           \
  } while (0)

__device__ inline short f2bf(float f) {
  union { float f; uint32_t u; } x; x.f = f;
  uint32_t u = x.u;
  u += 0x7fffu + ((u >> 16) & 1u);   // RNE
  return (short)(u >> 16);
}

#define BAR() do { asm volatile("" ::: "memory"); \
                   __builtin_amdgcn_s_barrier();  \
                   asm volatile("" ::: "memory"); } while (0)

// ---- fp32 -> bf16 convert (vectorized) ----------------------------------

__global__ __launch_bounds__(256) void cvt_f32_bf16(
    const float* __restrict__ in, short* __restrict__ out, int n4) {
  int i = blockIdx.x * 256 + threadIdx.x;
  if (i < n4) {
    float4 v = reinterpret_cast<const float4*>(in)[i];
    short4 o;
    o.x = f2bf(v.x); o.y = f2bf(v.y); o.z = f2bf(v.z); o.w = f2bf(v.w);
    reinterpret_cast<short4*>(out)[i] = o;
  }
}

// ---- GEMM: C[M,N] = A[M,K] @ B[N,K]^T, bf16 in, fp32 acc ---------------
// BEST VERIFIED (round 8): m201-style 8-phase with barrier-crossing
// reads and per-phase counted VM(10). 266 us/GEMM, MfmaUtil 45%,
// 0 bank conflicts, no spill.
//
// Per phase: {reads | 1 stage | [lgkm(8) if 12 reads]} -> BAR(mid) ->
//            LGKM(0) -> setprio(1) 16xMFMA setprio(0) -> VM(10) -> BAR.
//
// 256x256 tile, BK=64, 8 waves (2Mx4N), per-wave 128x64 = acc[8][4].
// LDS: 2 buf x 4 slots x [128x64] bf16 = 128 KiB; byte offsets:
// A0=+0, A1=+16384, B0=+32768, B1=+49152; buf1=+65536.
//
// Iter i = K-tiles 2i (buf0) / 2i+1 (buf1), 4 phases each.
// Reads: Ph1/5 a0q+bq0 (12), Ph2/6 bq1 (4), Ph3/7 a1q (8), Ph4/8 none.
// Stage stream: Ph1 A1(2i+1), Ph2 A0(2i+2), Ph3 B0(2i+2), Ph4 B1(2i+2),
//               Ph5 A1(2i+2), Ph6 A0(2i+3), Ph7 B0(2i+3), Ph8 B1(2i+3).
// Readiness ledger: each phase's read-halftile was staged 5 phases
// earlier with exactly 5 stages (10 gloads) issued after it -> VM(10)
// before the closing BAR of the PRECEDING phase guarantees it (vmcnt is
// per-wave; the barrier publishes "all waves' stages landed").
// Clobber ledger: every slot's restage is issued >=1 closing barrier
// after that slot's reads completed (reads complete at LGKM(0), before
// the same phase's closing BAR; restage is in a later phase).  All safe.
// Tail: last iteration peeled — only stage is Ph1's A1(nk-1); one VM(0)
// at Ph1-close drains everything; remaining tail phases need no VM.
// MFMA operands SWAPPED (mfma(b,a), verified r5/r6): lane&15 = M-row,
// 4 acc regs = 4 consecutive N-cols -> vectorized epilogue stores.
// EPI=0: bias+relu^2->bf16 (short4); EPI=1: bias->f32 (float4).

template <int EPI>
__global__ __launch_bounds__(512, 2) void gemm_bt(
    const short* __restrict__ A, const short* __restrict__ B,
    const float* __restrict__ bias, void* __restrict__ Cout,
    int M, int N, int K) {
  __shared__ __align__(16) short lds[2][4][128 * 64];

  const int tid  = threadIdx.x;
  const int wave = tid >> 6;
  const int lane = tid & 63;
  const int wr = wave >> 2;          // 0..1 -> M half (128 rows)
  const int wc = wave & 3;           // 0..3 -> N quarter (64 cols)
  const int fr = lane & 15, kq = lane >> 4;

  // T1: bijective XCD swizzle (nwg % 8 == 0), column-major in-chunk
  const int nwg = gridDim.x;
  const int w = (blockIdx.x & 7) * (nwg >> 3) + (blockIdx.x >> 3);
  const int gy = M >> 8;
  const int brow = w % gy;
  const int bcol = w / gy;

  f32x4 acc[8][4];
#pragma unroll
  for (int m = 0; m < 8; ++m)
#pragma unroll
    for (int n = 0; n < 4; ++n)
      acc[m][n] = (f32x4){0.f, 0.f, 0.f, 0.f};

  const int nk = K >> 6;             // K-tiles of 64 (even; nk>=4 here)

  // ---- T2 swizzle (within a 128x64 slot): granule g=r*8+gc stored at
  // P = g ^ (r&7). Verified 0 bank conflicts (rounds 2-13).
  const uint32_t LB = (uint32_t)(uintptr_t)&lds[0][0][0];
  uint32_t aA[4][2], aB[2][2];
#pragma unroll
  for (int m = 0; m < 4; ++m)
#pragma unroll
    for (int kk = 0; kk < 2; ++kk) {
      int r = wr * 64 + m * 16 + fr;
      int g = r * 8 + kk * 4 + kq;
      aA[m][kk] = LB + (uint32_t)((g ^ (r & 7)) * 16);
    }
#pragma unroll
  for (int n = 0; n < 2; ++n)
#pragma unroll
    for (int kk = 0; kk < 2; ++kk) {
      int r = wc * 32 + n * 16 + fr;
      int g = r * 8 + kk * 4 + kq;
      aB[n][kk] = LB + (uint32_t)((g ^ (r & 7)) * 16);
    }

  // ---- stage source addressing (inverse swizzle on global side)
  const int i0 = tid;
  const int gl0 = i0 ^ ((i0 >> 3) & 7);
  const int r0 = gl0 >> 3, c0 = gl0 & 7;
  const size_t rstep = (size_t)128 * K;

  const short* pA[2];
  const short* pB[2];
  {
    const int rb0 = (r0 >> 5) * 64 + (r0 & 31);
#pragma unroll
    for (int h = 0; h < 2; ++h) {
      pA[h] = A + (size_t)(brow * 256 + h * 64 + r0) * K + c0 * 8;
      pB[h] = B + (size_t)(bcol * 256 + rb0 + h * 32) * K + c0 * 8;
    }
  }

  const int dst0 = wave * 512, dst1 = 4096 + wave * 512;  // shorts in slot

#define STAGE(p, buf, slot)                              \
  do {                                                   \
    short* base_ = &lds[buf][slot][0];                   \
    gload_lds16((p), base_ + dst0);                      \
    gload_lds16((p) + rstep, base_ + dst1);              \
    (p) += 64;                                           \
  } while (0)

  // fragment regs + quadrant clusters (swapped operands)
  bf16x8 a0q[4][2], a1q[4][2], bq0[2][2], bq1[2][2];
  auto Q1 = [&]() {
#pragma unroll
    for (int m = 0; m < 4; ++m)
#pragma unroll
      for (int n = 0; n < 2; ++n)
#pragma unroll
        for (int kk = 0; kk < 2; ++kk)
          acc[m][n] = __builtin_amdgcn_mfma_f32_16x16x32_bf16(
              bq0[n][kk], a0q[m][kk], acc[m][n], 0, 0, 0);
  };
  auto Q2 = [&]() {
#pragma unroll
    for (int m = 0; m < 4; ++m)
#pragma unroll
      for (int n = 0; n < 2; ++n)
#pragma unroll
        for (int kk = 0; kk < 2; ++kk)
          acc[m][n + 2] = __builtin_amdgcn_mfma_f32_16x16x32_bf16(
              bq1[n][kk], a0q[m][kk], acc[m][n + 2], 0, 0, 0);
  };
  auto Q3 = [&]() {
#pragma unroll
    for (int m = 0; m < 4; ++m)
#pragma unroll
      for (int n = 0; n < 2; ++n)
#pragma unroll
        for (int kk = 0; kk < 2; ++kk)
          acc[m + 4][n + 2] = __builtin_amdgcn_mfma_f32_16x16x32_bf16(
              bq1[n][kk], a1q[m][kk], acc[m + 4][n + 2], 0, 0, 0);
  };
  auto Q4 = [&]() {
#pragma unroll
    for (int m = 0; m < 4; ++m)
#pragma unroll
      for (int n = 0; n < 2; ++n)
#pragma unroll
        for (int kk = 0; kk < 2; ++kk)
          acc[m + 4][n] = __builtin_amdgcn_mfma_f32_16x16x32_bf16(
              bq0[n][kk], a1q[m][kk], acc[m + 4][n], 0, 0, 0);
  };
  auto RD_A0 = [&](uint32_t cb) {
#pragma unroll
    for (int m = 0; m < 4; ++m)
#pragma unroll
      for (int kk = 0; kk < 2; ++kk)
        a0q[m][kk] = ds_readv(aA[m][kk] + cb);
  };
  auto RD_A1 = [&](uint32_t cb) {
#pragma unroll
    for (int m = 0; m < 4; ++m)
#pragma unroll
      for (int kk = 0; kk < 2; ++kk)
        a1q[m][kk] = ds_readv(aA[m][kk] + cb + 16384u);
  };
  auto RD_B0 = [&](uint32_t cb) {
#pragma unroll
    for (int n = 0; n < 2; ++n)
#pragma unroll
      for (int kk = 0; kk < 2; ++kk)
        bq0[n][kk] = ds_readv(aB[n][kk] + cb + 32768u);
  };
  auto RD_B1 = [&](uint32_t cb) {
#pragma unroll
    for (int n = 0; n < 2; ++n)
#pragma unroll
      for (int kk = 0; kk < 2; ++kk)
        bq1[n][kk] = ds_readv(aB[n][kk] + cb + 49152u);
  };

#define PRIO_ON  __builtin_amdgcn_s_setprio(1)
#define PRIO_OFF __builtin_amdgcn_s_setprio(0)

  // ---- prologue: tile0 full + tile1 {A0,B0,B1}; VM BEFORE BAR (publish).
  STAGE(pA[0], 0, 0);   // A0(0)
  STAGE(pB[0], 0, 2);   // B0(0)
  STAGE(pB[1], 0, 3);   // B1(0)
  STAGE(pA[1], 0, 1);   // A1(0)
  STAGE(pA[0], 1, 0);   // A0(1)
  STAGE(pB[0], 1, 2);   // B0(1)
  STAGE(pB[1], 1, 3);   // B1(1)
  VM(6);                // tile 0 (oldest 8) landed
  BAR();

  const int niter = nk >> 1;
  for (int i = 0; i < niter - 1; ++i) {
    // ============ K-tile 2i (buf0, cb=0) ============
    // Ph1
    RD_A0(0); RD_B0(0);
    STAGE(pA[1], 1, 1);                 // A1(2i+1)
    LGKM(8);
    BAR();
    LGKM(0);
    PRIO_ON; Q1(); PRIO_OFF;
    VM(10); BAR();
    // Ph2
    RD_B1(0);
    STAGE(pA[0], 0, 0);                 // A0(2i+2)
    BAR();
    LGKM(0);
    PRIO_ON; Q2(); PRIO_OFF;
    VM(10); BAR();
    // Ph3
    RD_A1(0);
    STAGE(pB[0], 0, 2);                 // B0(2i+2)
    BAR();
    LGKM(0);
    PRIO_ON; Q3(); PRIO_OFF;
    VM(10); BAR();
    // Ph4
    STAGE(pB[1], 0, 3);                 // B1(2i+2)
    BAR();
    PRIO_ON; Q4(); PRIO_OFF;
    VM(10); BAR();

    // ============ K-tile 2i+1 (buf1, cb=65536) ============
    // Ph5
    RD_A0(65536u); RD_B0(65536u);
    STAGE(pA[1], 0, 1);                 // A1(2i+2)
    LGKM(8);
    BAR();
    LGKM(0);
    PRIO_ON; Q1(); PRIO_OFF;
    VM(10); BAR();
    // Ph6
    RD_B1(65536u);
    STAGE(pA[0], 1, 0);                 // A0(2i+3)
    BAR();
    LGKM(0);
    PRIO_ON; Q2(); PRIO_OFF;
    VM(10); BAR();
    // Ph7
    RD_A1(65536u);
    STAGE(pB[0], 1, 2);                 // B0(2i+3)
    BAR();
    LGKM(0);
    PRIO_ON; Q3(); PRIO_OFF;
    VM(10); BAR();
    // Ph8
    STAGE(pB[1], 1, 3);                 // B1(2i+3)
    BAR();
    PRIO_ON; Q4(); PRIO_OFF;
    VM(10); BAR();
  }

  // ---- tail iteration (tiles nk-2 / nk-1): only stage = Ph1's A1(nk-1);
  // one VM(0) publish at Ph1-close, then drain-free phases.
  // Ph1
  RD_A0(0); RD_B0(0);
  STAGE(pA[1], 1, 1);                   // A1(nk-1)
  LGKM(8);
  BAR();
  LGKM(0);
  PRIO_ON; Q1(); PRIO_OFF;
  VM(0); BAR();                          // everything landed
  // Ph2
  RD_B1(0); BAR(); LGKM(0);
  PRIO_ON; Q2(); PRIO_OFF; BAR();
  // Ph3
  RD_A1(0); BAR(); LGKM(0);
  PRIO_ON; Q3(); PRIO_OFF; BAR();
  // Ph4
  PRIO_ON; Q4(); PRIO_OFF;
  BAR();
  // Ph5
  RD_A0(65536u); RD_B0(65536u); BAR(); LGKM(0);
  PRIO_ON; Q1(); PRIO_OFF; BAR();
  // Ph6
  RD_B1(65536u); BAR(); LGKM(0);
  PRIO_ON; Q2(); PRIO_OFF; BAR();
  // Ph7
  RD_A1(65536u); BAR(); LGKM(0);
  PRIO_ON; Q3(); PRIO_OFF; BAR();
  // Ph8
  PRIO_ON; Q4(); PRIO_OFF;

  // ---- epilogue (swapped-operand layout, verified r5-r13): row=m*16+fr,
  // cols = n*16 + q*4 + {0..3} -> 4-wide stores.
  const int q = lane >> 4;
  if (EPI == 0) {
    short* C = (short*)Cout;
#pragma unroll
    for (int m = 0; m < 8; ++m) {
      const int row = brow * 256 + wr * 128 + m * 16 + fr;
#pragma unroll
      for (int n = 0; n < 4; ++n) {
        const int col = bcol * 256 + wc * 64 + n * 16 + q * 4;
        const float4 bv = *(const float4*)&bias[col];
        short4 o;
        float v0 = acc[m][n][0] + bv.x; v0 = v0 > 0.f ? v0 * v0 : 0.f;
        float v1 = acc[m][n][1] + bv.y; v1 = v1 > 0.f ? v1 * v1 : 0.f;
        float v2 = acc[m][n][2] + bv.z; v2 = v2 > 0.f ? v2 * v2 : 0.f;
        float v3 = acc[m][n][3] + bv.w; v3 = v3 > 0.f ? v3 * v3 : 0.f;
        o.x = f2bf(v0); o.y = f2bf(v1); o.z = f2bf(v2); o.w = f2bf(v3);
        *(short4*)&C[(size_t)row * N + col] = o;
      }
    }
  } else {
    float* C = (float*)Cout;
#pragma unroll
    for (int m = 0; m < 8; ++m) {
      const int row = brow * 256 + wr * 128 + m * 16 + fr;
#pragma unroll
      for (int n = 0; n < 4; ++n) {
        const int col = bcol * 256 + wc * 64 + n * 16 + q * 4;
        const float4 bv = *(const float4*)&bias[col];
        float4 o;
        o.x = acc[m][n][0] + bv.x;
        o.y = acc[m][n][1] + bv.y;
        o.z = acc[m][n][2] + bv.z;
        o.w = acc[m][n][3] + bv.w;
        *(float4*)&C[(size_t)row * N + col] = o;
      }
    }
  }
#undef STAGE
}

// ---- launch -------------------------------------------------------------

extern "C" void kernel_launch(void* const* d_in, const int* in_sizes, int n_in,
                              void* d_out, int out_size, void* d_ws,
                              size_t ws_size, hipStream_t stream) {
  const float* x  = (const float*)d_in[0];
  const float* w1 = (const float*)d_in[1];
  const float* b1 = (const float*)d_in[2];
  const float* w2 = (const float*)d_in[3];
  const float* b2 = (const float*)d_in[4];
  float* out = (float*)d_out;

  const int H = in_sizes[2];            // 8192
  const int D = in_sizes[4];            // 2048
  const int M = in_sizes[0] / D;        // B*S = 8192

  short* xb  = (short*)d_ws;                 // M*D
  short* w1b = xb  + (size_t)M * D;          // H*D
  short* w2b = w1b + (size_t)H * D;          // D*H
  short* act = w2b + (size_t)D * H;          // M*H

  {
    int n4 = (M * D) / 4;
    cvt_f32_bf16<<<(n4 + 255) / 256, 256, 0, stream>>>(x, xb, n4);
    n4 = (H * D) / 4;
    cvt_f32_bf16<<<(n4 + 255) / 256, 256, 0, stream>>>(w1, w1b, n4);
    n4 = (D * H) / 4;
    cvt_f32_bf16<<<(n4 + 255) / 256, 256, 0, stream>>>(w2, w2b, n4);
  }

  // GEMM1: [M,D] @ [H,D]^T -> sqrelu -> act[M,H] (bf16)
  gemm_bt<0><<<(M / 256) * (H / 256), 512, 0, stream>>>(
      xb, w1b, b1, (void*)act, M, H, D);
  // GEMM2: [M,H] @ [D,H]^T -> + b2 -> out[M,D] (f32)
  gemm_bt<1><<<(M / 256) * (D / 256), 512, 0, stream>>>(
      act, w2b, b2, (void*)out, M, D, H);
}